// Round 7
// baseline (541.620 us; speedup 1.0000x reference)
//
#include <hip/hip_runtime.h>

// ---------------------------------------------------------------------------
// SimplicialAttentionLayer2 on MI355X (gfx950)
// N=4096, D=1024.  3x: S=(H@KV^T)/32 -> softmax -> *mask -> softmax -> @KV
// out = tanh(concat(H1,H2,H3) @ W^T + b)
// R11: instrumented revert.  GEMM body = R8 (proven 137.8us/941TF): full
// 24-read fragment read-ahead pinned by sched_barrier fences (R9/R10 let the
// compiler schedule reads late -> VGPR 92, serialized lgkm waits, -21%).
// Kept from R9: dsoftmax 2nd-max removal (logits in [0,1], max redundant).
// New: launch1 and launch2 use separately-named kernels (mgemm8/mgemm8f,
// shared inline body) so rocprof top-5 shows launch2+dsoftmax, resolving the
// ~150us the per-kernel arithmetic can't account for.
// Schedule: launch1 = S(768 blk)+GT(192 blk); dsoftmax; launch2 = split-K x4
// final GEMM (256 blk); combine4.
// ---------------------------------------------------------------------------

typedef unsigned short u16;
typedef unsigned int u32;
typedef __attribute__((ext_vector_type(8))) short short8;
typedef __attribute__((ext_vector_type(4))) float floatx4;

#define NS 4096
#define DF 1024

__device__ __forceinline__ u16 f2b(float x) {          // fp32 -> bf16 RNE
    u32 u = __float_as_uint(x);
    u32 r = (u + 0x7fffu + ((u >> 16) & 1u)) >> 16;
    return (u16)r;
}
__device__ __forceinline__ u32 packb(float a, float b) {
    return (u32)f2b(a) | ((u32)f2b(b) << 16);
}
__device__ __forceinline__ void unpack8(uint4 u, float* v) {
    v[0] = __uint_as_float(u.x << 16); v[1] = __uint_as_float(u.x & 0xffff0000u);
    v[2] = __uint_as_float(u.y << 16); v[3] = __uint_as_float(u.y & 0xffff0000u);
    v[4] = __uint_as_float(u.z << 16); v[5] = __uint_as_float(u.z & 0xffff0000u);
    v[6] = __uint_as_float(u.w << 16); v[7] = __uint_as_float(u.w & 0xffff0000u);
}

// ---------------------------------------------------------------------------
// 256x256 tile, BK=64, 512 threads = 8 waves (2 M x 4 N), per-wave 128x64.
// LDS: 2 dbuf x (A 32KB + B 32KB) = 128 KiB.  NT gemm: C = epi(alpha*A@B^T).
//   epi 0: bf16 store (alpha applied);  epi 1: fp32 store raw acc
// Swizzle: 16B-chunk p at row r holds logical chunk p^(r&7)
// (pre-swizzled global source + swizzled ds_read, linear LDS dest).
// ---------------------------------------------------------------------------
struct GemmDesc {
    const u16* A; const u16* B; void* C;
    const float* bias;
    int K, lda, ldb, ldc, nTilesX, nTilesY, nBlocks, colMajor, epi;
    float alpha;
};

// stage full 256x64 A and B tiles (4+4 global_load_lds per thread)
__device__ __forceinline__ void stage_tile(
    const u16* __restrict__ Ab, const u16* __restrict__ Bb,
    int lda, int ldb, int kt, u16* as, u16* bs, int tid)
{
    const int wave = tid >> 6;
#pragma unroll
    for (int i = 0; i < 4; i++) {
        int chunk = i * 512 + tid;
        int row   = chunk >> 3;                     // 8 chunks per 128B row
        int l     = (chunk & 7) ^ (row & 7);        // pre-swizzled source
        const u16* ga = Ab + (size_t)row * lda + kt + l * 8;
        __builtin_amdgcn_global_load_lds(
            (const __attribute__((address_space(1))) void*)ga,
            (__attribute__((address_space(3))) void*)&as[(i * 512 + wave * 64) * 8],
            16, 0, 0);
    }
#pragma unroll
    for (int i = 0; i < 4; i++) {
        int chunk = i * 512 + tid;
        int row   = chunk >> 3;
        int l     = (chunk & 7) ^ (row & 7);
        const u16* gb = Bb + (size_t)row * ldb + kt + l * 8;
        __builtin_amdgcn_global_load_lds(
            (const __attribute__((address_space(1))) void*)gb,
            (__attribute__((address_space(3))) void*)&bs[(i * 512 + wave * 64) * 8],
            16, 0, 0);
    }
}

__device__ __forceinline__ void gemm8_body(
    const GemmDesc& rd0, const GemmDesc& rd1,
    const GemmDesc& rd2, const GemmDesc& rd3,
    u16 (&As)[2][256 * 64], u16 (&Bs)[2][256 * 64])
{
    int bid = blockIdx.x;
    const GemmDesc* d;
    if (bid < rd0.nBlocks) d = &rd0;
    else {
        bid -= rd0.nBlocks;
        if (bid < rd1.nBlocks) d = &rd1;
        else {
            bid -= rd1.nBlocks;
            if (bid < rd2.nBlocks) d = &rd2;
            else { bid -= rd2.nBlocks; d = &rd3; }
        }
    }

    const int tid  = threadIdx.x;
    const int lane = tid & 63;
    const int wave = tid >> 6;
    const int wm = wave >> 2, wn = wave & 3;        // 2 x 4 wave grid
    const int q = lane >> 4, r16 = lane & 15;

    int bm, bn;
    if (d->colMajor) { bm = bid % d->nTilesY; bn = bid / d->nTilesY; }
    else             { bn = bid % d->nTilesX; bm = bid / d->nTilesX; }

    const u16* Ab = d->A + (size_t)bm * 256 * d->lda;
    const u16* Bb = d->B + (size_t)bn * 256 * d->ldb;
    const int lda = d->lda, ldb = d->ldb;
    const int nkt = d->K >> 6;                       // requires nkt >= 2

    floatx4 acc[8][4];
#pragma unroll
    for (int i = 0; i < 8; i++)
#pragma unroll
        for (int j = 0; j < 4; j++) acc[i][j] = (floatx4){0.f, 0.f, 0.f, 0.f};

    // prologue: stage tile 0 into buf 0; __syncthreads drains vmcnt
    stage_tile(Ab, Bb, lda, ldb, 0, As[0], Bs[0], tid);
    __syncthreads();

    for (int t = 0; t < nkt; ++t) {
        const int cur = t & 1, nxt = cur ^ 1;
        const u16* aw = As[cur];
        const u16* bw = Bs[cur];
        short8 af[8][2], bq[4][2];

        // issue all frag reads: kk=0 batch first, then kk=1 (read-ahead)
#pragma unroll
        for (int kk = 0; kk < 2; kk++) {
#pragma unroll
            for (int ni = 0; ni < 4; ni++) {
                int row  = wn * 64 + ni * 16 + r16;
                int phys = (kk * 4 + q) ^ (row & 7);
                bq[ni][kk] = *(const short8*)&bw[row * 64 + phys * 8];
            }
#pragma unroll
            for (int mi = 0; mi < 8; mi++) {
                int row  = wm * 128 + mi * 16 + r16;
                int phys = (kk * 4 + q) ^ (row & 7);
                af[mi][kk] = *(const short8*)&aw[row * 64 + phys * 8];
            }
        }
        // stage tile t+1 into the buffer freed at the previous barrier
        if (t + 1 < nkt)
            stage_tile(Ab, Bb, lda, ldb, (t + 1) << 6, As[nxt], Bs[nxt], tid);
        __builtin_amdgcn_sched_barrier(0);   // reads+stages stay above MFMA

        // kk=0 cluster: gated by compiler's counted lgkmcnt on first batch
        __builtin_amdgcn_s_setprio(1);
#pragma unroll
        for (int mi = 0; mi < 8; mi++)
#pragma unroll
            for (int ni = 0; ni < 4; ni++)
                acc[mi][ni] = __builtin_amdgcn_mfma_f32_16x16x32_bf16(
                    af[mi][0], bq[ni][0], acc[mi][ni], 0, 0, 0);
        __builtin_amdgcn_s_setprio(0);
        __builtin_amdgcn_sched_barrier(0);   // keep kk clusters separate

        // kk=1 cluster: its reads were issued ~one cluster ago
        __builtin_amdgcn_s_setprio(1);
#pragma unroll
        for (int mi = 0; mi < 8; mi++)
#pragma unroll
            for (int ni = 0; ni < 4; ni++)
                acc[mi][ni] = __builtin_amdgcn_mfma_f32_16x16x32_bf16(
                    af[mi][1], bq[ni][1], acc[mi][ni], 0, 0, 0);
        __builtin_amdgcn_s_setprio(0);
        __builtin_amdgcn_sched_barrier(0);

        // single boundary barrier: drains vmcnt (stages aged a full tile)
        // and publishes buf[nxt]; protects stages of t+2 into buf[cur].
        if (t + 1 < nkt) __syncthreads();
    }

    // epilogue: D element (row = q*4 + r, col = lane&15)
    const int ldc = d->ldc;
#pragma unroll
    for (int mi = 0; mi < 8; mi++) {
#pragma unroll
        for (int ni = 0; ni < 4; ni++) {
            floatx4 v = acc[mi][ni];
            int col  = bn * 256 + wn * 64 + ni * 16 + r16;
            int rowb = bm * 256 + wm * 128 + mi * 16 + q * 4;
            if (d->epi == 0) {
                u16* C = (u16*)d->C;
#pragma unroll
                for (int r = 0; r < 4; r++)
                    C[(size_t)(rowb + r) * ldc + col] = f2b(v[r] * d->alpha);
            } else {
                float* C = (float*)d->C;
#pragma unroll
                for (int r = 0; r < 4; r++)
                    C[(size_t)(rowb + r) * ldc + col] = v[r];
            }
        }
    }
}

// two identically-bodied kernels: separate names -> separate rocprof rows
__global__ __launch_bounds__(512, 2)
void mgemm8(GemmDesc d0, GemmDesc d1, GemmDesc d2, GemmDesc d3)
{
    __shared__ u16 As[2][256 * 64];
    __shared__ u16 Bs[2][256 * 64];
    gemm8_body(d0, d1, d2, d3, As, Bs);
}

__global__ __launch_bounds__(512, 2)
void mgemm8f(GemmDesc d0, GemmDesc d1, GemmDesc d2, GemmDesc d3)
{
    __shared__ u16 As[2][256 * 64];
    __shared__ u16 Bs[2][256 * 64];
    gemm8_body(d0, d1, d2, d3, As, Bs);
}

// ---------------------------------------------------------------------------
// Double softmax, branch-routed: grid = 3*4096 blocks; branch = bid>>12.
// Row = 4096 bf16 at stride ldS, in-place. Mask: fp32 mF (!=0) or bit mask mB.
// ---------------------------------------------------------------------------
struct SmDesc { u16* S; const float* mF; const u32* mB; };

__device__ __forceinline__ float blockMax(float x, volatile float* red) {
#pragma unroll
    for (int off = 32; off > 0; off >>= 1) x = fmaxf(x, __shfl_xor(x, off, 64));
    __syncthreads();
    if ((threadIdx.x & 63) == 0) red[threadIdx.x >> 6] = x;
    __syncthreads();
    return fmaxf(fmaxf(red[0], red[1]), fmaxf(red[2], red[3]));
}
__device__ __forceinline__ float blockSum(float x, volatile float* red) {
#pragma unroll
    for (int off = 32; off > 0; off >>= 1) x += __shfl_xor(x, off, 64);
    __syncthreads();
    if ((threadIdx.x & 63) == 0) red[threadIdx.x >> 6] = x;
    __syncthreads();
    return red[0] + red[1] + red[2] + red[3];
}

__global__ __launch_bounds__(256)
void dsoftmax3(SmDesc d0, SmDesc d1, SmDesc d2, int ldS)
{
    __shared__ float red[4];
    const int bid = blockIdx.x;
    const int br  = bid >> 12;
    const int row = bid & 4095;
    const SmDesc d = (br == 0) ? d0 : (br == 1) ? d1 : d2;
    u16* Srow = d.S + (size_t)row * ldS;
    const int t = threadIdx.x;

    float v[16];
    uint4 u0 = ((const uint4*)Srow)[t * 2];
    uint4 u1 = ((const uint4*)Srow)[t * 2 + 1];
    unpack8(u0, v); unpack8(u1, v + 8);

    float m = -1e30f;
#pragma unroll
    for (int j = 0; j < 16; j++) m = fmaxf(m, v[j]);
    m = blockMax(m, red);

    float s = 0.f;
#pragma unroll
    for (int j = 0; j < 16; j++) { v[j] = __expf(v[j] - m); s += v[j]; }
    s = blockSum(s, red);
    float rz = 1.0f / s;

    float v2[16];
    if (d.mF) {
        const float* mrow = d.mF + (size_t)row * NS;
#pragma unroll
        for (int k = 0; k < 4; k++) {
            float4 mv = ((const float4*)mrow)[t * 4 + k];
            v2[k * 4 + 0] = (mv.x != 0.f) ? v[k * 4 + 0] * rz : 0.f;
            v2[k * 4 + 1] = (mv.y != 0.f) ? v[k * 4 + 1] * rz : 0.f;
            v2[k * 4 + 2] = (mv.z != 0.f) ? v[k * 4 + 2] * rz : 0.f;
            v2[k * 4 + 3] = (mv.w != 0.f) ? v[k * 4 + 3] * rz : 0.f;
        }
    } else {
        u32 w = d.mB[(size_t)row * (NS / 32) + (t >> 1)];
        u32 half = (w >> ((t & 1) * 16)) & 0xffffu;
#pragma unroll
        for (int j = 0; j < 16; j++)
            v2[j] = ((half >> j) & 1u) ? v[j] * rz : 0.f;
    }

    // second softmax: logits v2 in [0,1] (probabilities x 0/1 mask), so
    // exp never overflows -> max-subtraction is mathematically redundant.
    float s2 = 0.f;
#pragma unroll
    for (int j = 0; j < 16; j++) { v2[j] = __expf(v2[j]); s2 += v2[j]; }
    s2 = blockSum(s2, red);
    float rz2 = 1.0f / s2;

    uint4 o0, o1;
    o0.x = packb(v2[0] * rz2,  v2[1] * rz2);
    o0.y = packb(v2[2] * rz2,  v2[3] * rz2);
    o0.z = packb(v2[4] * rz2,  v2[5] * rz2);
    o0.w = packb(v2[6] * rz2,  v2[7] * rz2);
    o1.x = packb(v2[8] * rz2,  v2[9] * rz2);
    o1.y = packb(v2[10] * rz2, v2[11] * rz2);
    o1.z = packb(v2[12] * rz2, v2[13] * rz2);
    o1.w = packb(v2[14] * rz2, v2[15] * rz2);
    ((uint4*)Srow)[t * 2]     = o0;
    ((uint4*)Srow)[t * 2 + 1] = o1;
}

// ---------------------------------------------------------------------------
// fp32 [NS,DF] x3 -> bf16 [3*NS, DF] contiguous
// ---------------------------------------------------------------------------
__global__ __launch_bounds__(256)
void cvt_h3(const float* __restrict__ X0, const float* __restrict__ X1,
            const float* __restrict__ X2, u16* __restrict__ Y)
{
    const float* X = (blockIdx.z == 0) ? X0 : (blockIdx.z == 1) ? X1 : X2;
    u16* Yb = Y + (size_t)blockIdx.z * NS * DF;
    int i = blockIdx.x * 256 + threadIdx.x;       // float4 index
    float4 x = ((const float4*)X)[i];
    ushort4 y;
    y.x = f2b(x.x); y.y = f2b(x.y); y.z = f2b(x.z); y.w = f2b(x.w);
    ((ushort4*)Yb)[i] = y;
}

// bit-packed transposed nonzero mask: MT[c*(n/32)+w] bit b = (X[w*32+b][c]!=0)
__global__ __launch_bounds__(256)
void mask_bits(const float* __restrict__ X, u32* __restrict__ MT, int n)
{
    __shared__ float tile[32][33];
    const int tx = threadIdx.x, ty = threadIdx.y;
    const int bx = blockIdx.x * 32, by = blockIdx.y * 32;
#pragma unroll
    for (int k = 0; k < 4; k++) {
        int r = by + ty + k * 8;
        tile[ty + k * 8][tx] = X[(size_t)r * n + bx + tx];
    }
    __syncthreads();
#pragma unroll
    for (int k = 0; k < 4; k++) {
        int c = bx + ty + k * 8;
        unsigned long long m = __ballot(tile[tx][ty + k * 8] != 0.f);
        u32 w = (ty & 1) ? (u32)(m >> 32) : (u32)m;
        if (tx == 0) MT[(size_t)c * (n / 32) + (by >> 5)] = w;
    }
}

__global__ __launch_bounds__(256)
void cvtk(const float* __restrict__ X, u16* __restrict__ Y, int n4)
{
    int i = blockIdx.x * 256 + threadIdx.x;
    if (i >= n4) return;
    float4 x = ((const float4*)X)[i];
    ushort4 y;
    y.x = f2b(x.x); y.y = f2b(x.y); y.z = f2b(x.z); y.w = f2b(x.w);
    ((ushort4*)Y)[i] = y;
}

// out = tanh(out + P1 + P2 + P3 + bias[col]); 4096x1024 fp32, float4/thread.
__global__ __launch_bounds__(256)
void combine4(const float* __restrict__ P1, const float* __restrict__ P2,
              const float* __restrict__ P3, const float* __restrict__ bias,
              float* __restrict__ out)
{
    int i = blockIdx.x * 256 + threadIdx.x;       // float4 index
    float4 a = ((const float4*)out)[i];
    float4 b = ((const float4*)P1)[i];
    float4 c = ((const float4*)P2)[i];
    float4 e = ((const float4*)P3)[i];
    float4 bb = ((const float4*)bias)[i & 255];   // 1024 cols = 256 float4
    float4 o;
    o.x = tanhf(a.x + b.x + c.x + e.x + bb.x);
    o.y = tanhf(a.y + b.y + c.y + e.y + bb.y);
    o.z = tanhf(a.z + b.z + c.z + e.z + bb.z);
    o.w = tanhf(a.w + b.w + c.w + e.w + bb.w);
    ((float4*)out)[i] = o;
}

// ---------------------------------------------------------------------------
static inline GemmDesc mk8(const u16* A, const u16* B, void* C,
                           int K, int lda, int ldb, int ldc,
                           int nTX, int nTY, int epi, float alpha,
                           int colMajor)
{
    GemmDesc d;
    d.A = A; d.B = B; d.C = C; d.bias = nullptr;
    d.K = K; d.lda = lda; d.ldb = ldb; d.ldc = ldc;
    d.nTilesX = nTX; d.nTilesY = nTY; d.nBlocks = nTX * nTY;
    d.colMajor = colMajor; d.epi = epi; d.alpha = alpha;
    return d;
}

extern "C" void kernel_launch(void* const* d_in, const int* in_sizes, int n_in,
                              void* d_out, int out_size, void* d_ws, size_t ws_size,
                              hipStream_t stream)
{
    const float* L      = (const float*)d_in[0];
    const float* H      = (const float*)d_in[1];
    const float* B_low  = (const float*)d_in[2];
    const float* H_low  = (const float*)d_in[3];
    const float* B_high = (const float*)d_in[4];
    const float* H_high = (const float*)d_in[5];
    const float* W      = (const float*)d_in[6];
    const float* bvec   = (const float*)d_in[7];
    float* out = (float*)d_out;

    const size_t MB = 1024 * 1024;
    char* ws = (char*)d_ws;
    dim3 bt(32, 8);

    // ---- workspace layout (168 MB peak, 176 MB budget) ----
    u16* S    = (u16*)(ws + 0);             // 96 MB [4096, 12288] bf16
    u16* Hcat = (u16*)(ws + 96 * MB);       // 24 MB [12288, 1024] bf16
    u16* Wb   = (u16*)(ws + 120 * MB);      //  6 MB [1024, 3072] bf16
    u32* mlT  = (u32*)(ws + 126 * MB);      //  2 MB bit mask
    u16* GT   = (u16*)(ws + 128 * MB);      // 24 MB [1024, 12288] bf16
    float* P1 = (float*)(ws + 96 * MB);     // 16 MB (over dead Hcat)
    float* P2 = (float*)(ws + 112 * MB);    // 16 MB (over dead Hcat/Wb/mlT)
    float* P3 = (float*)(ws + 152 * MB);    // 16 MB

    cvt_h3<<<dim3(NS * DF / 4 / 256, 1, 3), 256, 0, stream>>>(H, H_low, H_high, Hcat);
    cvtk<<<(DF * 3 * DF / 4 + 255) / 256, 256, 0, stream>>>(W, Wb, DF * 3 * DF / 4);
    mask_bits<<<dim3(NS / 32, NS / 32), bt, 0, stream>>>(B_low, mlT, NS);

    // launch1: S = (Hcat @ Hcat^T)/32 (768 blocks) and
    //          GT_b = W_b-block @ KV_b^T (3 x 64 blocks), all K=1024 uniform.
    GemmDesc sg = mk8(Hcat, Hcat, S, DF, DF, DF, 3 * NS,
                      3 * NS / 256, NS / 256, 0, 0.03125f, 1);
    GemmDesc g0 = mk8(Wb,          Hcat,               GT,          DF, 3 * DF, DF, 3 * NS, NS / 256, DF / 256, 0, 1.0f, 1);
    GemmDesc g1 = mk8(Wb + DF,     Hcat + NS * DF,     GT + NS,     DF, 3 * DF, DF, 3 * NS, NS / 256, DF / 256, 0, 1.0f, 1);
    GemmDesc g2 = mk8(Wb + 2 * DF, Hcat + 2 * NS * DF, GT + 2 * NS, DF, 3 * DF, DF, 3 * NS, NS / 256, DF / 256, 0, 1.0f, 1);
    mgemm8<<<sg.nBlocks + g0.nBlocks + g1.nBlocks + g2.nBlocks, 512, 0, stream>>>(sg, g0, g1, g2);

    // fused double softmax over 12288 rows (row stride 12288), in place
    SmDesc s0 = {S,          L,       nullptr};
    SmDesc s1 = {S + NS,     nullptr, mlT};
    SmDesc s2 = {S + 2 * NS, B_high,  nullptr};
    dsoftmax3<<<3 * NS, 256, 0, stream>>>(s0, s1, s2, 3 * NS);

    // launch2: out_pre = A_all @ GT^T, split-K x4 (K=3072 chunks), 256 blocks
    GemmDesc f0 = mk8(S,          GT,          out, 3 * DF, 3 * NS, 3 * NS, DF, DF / 256, NS / 256, 1, 1.0f, 1);
    GemmDesc f1 = mk8(S + 3 * DF, GT + 3 * DF, P1,  3 * DF, 3 * NS, 3 * NS, DF, DF / 256, NS / 256, 1, 1.0f, 1);
    GemmDesc f2 = mk8(S + 6 * DF, GT + 6 * DF, P2,  3 * DF, 3 * NS, 3 * NS, DF, DF / 256, NS / 256, 1, 1.0f, 1);
    GemmDesc f3 = mk8(S + 9 * DF, GT + 9 * DF, P3,  3 * DF, 3 * NS, 3 * NS, DF, DF / 256, NS / 256, 1, 1.0f, 1);
    mgemm8f<<<f0.nBlocks + f1.nBlocks + f2.nBlocks + f3.nBlocks, 512, 0, stream>>>(f0, f1, f2, f3);

    // out = tanh(out + P1 + P2 + P3 + bias)
    combine4<<<NS * DF / 4 / 256, 256, 0, stream>>>(P1, P2, P3, bvec, out);
}

// Round 8
// 486.626 us; speedup vs baseline: 1.1130x; 1.1130x over previous
//
#include <hip/hip_runtime.h>

// ---------------------------------------------------------------------------
// SimplicialAttentionLayer2 on MI355X (gfx950)
// N=4096, D=1024.  3x: S=(H@KV^T)/32 -> softmax -> *mask -> softmax -> @KV
// out = tanh(concat(H1,H2,H3) @ W^T + b)
// R12: re-anchor on R8 (proven 501.7us).  GEMM kernel restored byte-identical
// to R8 (by-value GemmDesc, in-kernel desc select, full 24-read fragment
// read-ahead pinned by sched_barrier, single boundary __syncthreads).
// dsoftmax restored to R8 form (WITH second max) to remove the last
// confound vs R10/R11's +40us.  ONLY addition: mgemm8f = verbatim textual
// duplicate of mgemm8 (independent codegen, no shared device function),
// used for launch2 so rocprof finally shows launch2 separately.
// Schedule: launch1 = S(768 blk)+GT(192 blk); dsoftmax; launch2 = split-K x4
// final GEMM (256 blk); combine4.
// ---------------------------------------------------------------------------

typedef unsigned short u16;
typedef unsigned int u32;
typedef __attribute__((ext_vector_type(8))) short short8;
typedef __attribute__((ext_vector_type(4))) float floatx4;

#define NS 4096
#define DF 1024

__device__ __forceinline__ u16 f2b(float x) {          // fp32 -> bf16 RNE
    u32 u = __float_as_uint(x);
    u32 r = (u + 0x7fffu + ((u >> 16) & 1u)) >> 16;
    return (u16)r;
}
__device__ __forceinline__ u32 packb(float a, float b) {
    return (u32)f2b(a) | ((u32)f2b(b) << 16);
}
__device__ __forceinline__ void unpack8(uint4 u, float* v) {
    v[0] = __uint_as_float(u.x << 16); v[1] = __uint_as_float(u.x & 0xffff0000u);
    v[2] = __uint_as_float(u.y << 16); v[3] = __uint_as_float(u.y & 0xffff0000u);
    v[4] = __uint_as_float(u.z << 16); v[5] = __uint_as_float(u.z & 0xffff0000u);
    v[6] = __uint_as_float(u.w << 16); v[7] = __uint_as_float(u.w & 0xffff0000u);
}

// ---------------------------------------------------------------------------
// 256x256 tile, BK=64, 512 threads = 8 waves (2 M x 4 N), per-wave 128x64.
// LDS: 2 dbuf x (A 32KB + B 32KB) = 128 KiB.  NT gemm: C = epi(alpha*A@B^T).
//   epi 0: bf16 store (alpha applied);  epi 1: fp32 store raw acc
// Swizzle: 16B-chunk p at row r holds logical chunk p^(r&7)
// (pre-swizzled global source + swizzled ds_read, linear LDS dest).
// ---------------------------------------------------------------------------
struct GemmDesc {
    const u16* A; const u16* B; void* C;
    const float* bias;
    int K, lda, ldb, ldc, nTilesX, nTilesY, nBlocks, colMajor, epi;
    float alpha;
};

// stage full 256x64 A and B tiles (4+4 global_load_lds per thread)
__device__ __forceinline__ void stage_tile(
    const u16* __restrict__ Ab, const u16* __restrict__ Bb,
    int lda, int ldb, int kt, u16* as, u16* bs, int tid)
{
    const int wave = tid >> 6;
#pragma unroll
    for (int i = 0; i < 4; i++) {
        int chunk = i * 512 + tid;
        int row   = chunk >> 3;                     // 8 chunks per 128B row
        int l     = (chunk & 7) ^ (row & 7);        // pre-swizzled source
        const u16* ga = Ab + (size_t)row * lda + kt + l * 8;
        __builtin_amdgcn_global_load_lds(
            (const __attribute__((address_space(1))) void*)ga,
            (__attribute__((address_space(3))) void*)&as[(i * 512 + wave * 64) * 8],
            16, 0, 0);
    }
#pragma unroll
    for (int i = 0; i < 4; i++) {
        int chunk = i * 512 + tid;
        int row   = chunk >> 3;
        int l     = (chunk & 7) ^ (row & 7);
        const u16* gb = Bb + (size_t)row * ldb + kt + l * 8;
        __builtin_amdgcn_global_load_lds(
            (const __attribute__((address_space(1))) void*)gb,
            (__attribute__((address_space(3))) void*)&bs[(i * 512 + wave * 64) * 8],
            16, 0, 0);
    }
}

__global__ __launch_bounds__(512, 2)
void mgemm8(GemmDesc d0, GemmDesc d1, GemmDesc d2, GemmDesc d3)
{
    __shared__ u16 As[2][256 * 64];
    __shared__ u16 Bs[2][256 * 64];

    int bid = blockIdx.x;
    const GemmDesc* d;
    if (bid < d0.nBlocks) d = &d0;
    else {
        bid -= d0.nBlocks;
        if (bid < d1.nBlocks) d = &d1;
        else {
            bid -= d1.nBlocks;
            if (bid < d2.nBlocks) d = &d2;
            else { bid -= d2.nBlocks; d = &d3; }
        }
    }

    const int tid  = threadIdx.x;
    const int lane = tid & 63;
    const int wave = tid >> 6;
    const int wm = wave >> 2, wn = wave & 3;        // 2 x 4 wave grid
    const int q = lane >> 4, r16 = lane & 15;

    int bm, bn;
    if (d->colMajor) { bm = bid % d->nTilesY; bn = bid / d->nTilesY; }
    else             { bn = bid % d->nTilesX; bm = bid / d->nTilesX; }

    const u16* Ab = d->A + (size_t)bm * 256 * d->lda;
    const u16* Bb = d->B + (size_t)bn * 256 * d->ldb;
    const int lda = d->lda, ldb = d->ldb;
    const int nkt = d->K >> 6;                       // requires nkt >= 2

    floatx4 acc[8][4];
#pragma unroll
    for (int i = 0; i < 8; i++)
#pragma unroll
        for (int j = 0; j < 4; j++) acc[i][j] = (floatx4){0.f, 0.f, 0.f, 0.f};

    // prologue: stage tile 0 into buf 0; __syncthreads drains vmcnt
    stage_tile(Ab, Bb, lda, ldb, 0, As[0], Bs[0], tid);
    __syncthreads();

    for (int t = 0; t < nkt; ++t) {
        const int cur = t & 1, nxt = cur ^ 1;
        const u16* aw = As[cur];
        const u16* bw = Bs[cur];
        short8 af[8][2], bq[4][2];

        // issue all frag reads: kk=0 batch first, then kk=1 (read-ahead)
#pragma unroll
        for (int kk = 0; kk < 2; kk++) {
#pragma unroll
            for (int ni = 0; ni < 4; ni++) {
                int row  = wn * 64 + ni * 16 + r16;
                int phys = (kk * 4 + q) ^ (row & 7);
                bq[ni][kk] = *(const short8*)&bw[row * 64 + phys * 8];
            }
#pragma unroll
            for (int mi = 0; mi < 8; mi++) {
                int row  = wm * 128 + mi * 16 + r16;
                int phys = (kk * 4 + q) ^ (row & 7);
                af[mi][kk] = *(const short8*)&aw[row * 64 + phys * 8];
            }
        }
        // stage tile t+1 into the buffer freed at the previous barrier
        if (t + 1 < nkt)
            stage_tile(Ab, Bb, lda, ldb, (t + 1) << 6, As[nxt], Bs[nxt], tid);
        __builtin_amdgcn_sched_barrier(0);   // reads+stages stay above MFMA

        // kk=0 cluster: gated by compiler's counted lgkmcnt on first batch
        __builtin_amdgcn_s_setprio(1);
#pragma unroll
        for (int mi = 0; mi < 8; mi++)
#pragma unroll
            for (int ni = 0; ni < 4; ni++)
                acc[mi][ni] = __builtin_amdgcn_mfma_f32_16x16x32_bf16(
                    af[mi][0], bq[ni][0], acc[mi][ni], 0, 0, 0);
        __builtin_amdgcn_s_setprio(0);
        __builtin_amdgcn_sched_barrier(0);   // keep kk clusters separate

        // kk=1 cluster: its reads were issued ~one cluster ago
        __builtin_amdgcn_s_setprio(1);
#pragma unroll
        for (int mi = 0; mi < 8; mi++)
#pragma unroll
            for (int ni = 0; ni < 4; ni++)
                acc[mi][ni] = __builtin_amdgcn_mfma_f32_16x16x32_bf16(
                    af[mi][1], bq[ni][1], acc[mi][ni], 0, 0, 0);
        __builtin_amdgcn_s_setprio(0);
        __builtin_amdgcn_sched_barrier(0);

        // single boundary barrier: drains vmcnt (stages aged a full tile)
        // and publishes buf[nxt]; protects stages of t+2 into buf[cur].
        if (t + 1 < nkt) __syncthreads();
    }

    // epilogue: D element (row = q*4 + r, col = lane&15)
    const int ldc = d->ldc;
#pragma unroll
    for (int mi = 0; mi < 8; mi++) {
#pragma unroll
        for (int ni = 0; ni < 4; ni++) {
            floatx4 v = acc[mi][ni];
            int col  = bn * 256 + wn * 64 + ni * 16 + r16;
            int rowb = bm * 256 + wm * 128 + mi * 16 + q * 4;
            if (d->epi == 0) {
                u16* C = (u16*)d->C;
#pragma unroll
                for (int r = 0; r < 4; r++)
                    C[(size_t)(rowb + r) * ldc + col] = f2b(v[r] * d->alpha);
            } else {
                float* C = (float*)d->C;
#pragma unroll
                for (int r = 0; r < 4; r++)
                    C[(size_t)(rowb + r) * ldc + col] = v[r];
            }
        }
    }
}

// verbatim duplicate of mgemm8 (independent codegen) — used for launch2 so
// rocprof reports it as a separate kernel row.
__global__ __launch_bounds__(512, 2)
void mgemm8f(GemmDesc d0, GemmDesc d1, GemmDesc d2, GemmDesc d3)
{
    __shared__ u16 As[2][256 * 64];
    __shared__ u16 Bs[2][256 * 64];

    int bid = blockIdx.x;
    const GemmDesc* d;
    if (bid < d0.nBlocks) d = &d0;
    else {
        bid -= d0.nBlocks;
        if (bid < d1.nBlocks) d = &d1;
        else {
            bid -= d1.nBlocks;
            if (bid < d2.nBlocks) d = &d2;
            else { bid -= d2.nBlocks; d = &d3; }
        }
    }

    const int tid  = threadIdx.x;
    const int lane = tid & 63;
    const int wave = tid >> 6;
    const int wm = wave >> 2, wn = wave & 3;        // 2 x 4 wave grid
    const int q = lane >> 4, r16 = lane & 15;

    int bm, bn;
    if (d->colMajor) { bm = bid % d->nTilesY; bn = bid / d->nTilesY; }
    else             { bn = bid % d->nTilesX; bm = bid / d->nTilesX; }

    const u16* Ab = d->A + (size_t)bm * 256 * d->lda;
    const u16* Bb = d->B + (size_t)bn * 256 * d->ldb;
    const int lda = d->lda, ldb = d->ldb;
    const int nkt = d->K >> 6;                       // requires nkt >= 2

    floatx4 acc[8][4];
#pragma unroll
    for (int i = 0; i < 8; i++)
#pragma unroll
        for (int j = 0; j < 4; j++) acc[i][j] = (floatx4){0.f, 0.f, 0.f, 0.f};

    // prologue: stage tile 0 into buf 0; __syncthreads drains vmcnt
    stage_tile(Ab, Bb, lda, ldb, 0, As[0], Bs[0], tid);
    __syncthreads();

    for (int t = 0; t < nkt; ++t) {
        const int cur = t & 1, nxt = cur ^ 1;
        const u16* aw = As[cur];
        const u16* bw = Bs[cur];
        short8 af[8][2], bq[4][2];

        // issue all frag reads: kk=0 batch first, then kk=1 (read-ahead)
#pragma unroll
        for (int kk = 0; kk < 2; kk++) {
#pragma unroll
            for (int ni = 0; ni < 4; ni++) {
                int row  = wn * 64 + ni * 16 + r16;
                int phys = (kk * 4 + q) ^ (row & 7);
                bq[ni][kk] = *(const short8*)&bw[row * 64 + phys * 8];
            }
#pragma unroll
            for (int mi = 0; mi < 8; mi++) {
                int row  = wm * 128 + mi * 16 + r16;
                int phys = (kk * 4 + q) ^ (row & 7);
                af[mi][kk] = *(const short8*)&aw[row * 64 + phys * 8];
            }
        }
        // stage tile t+1 into the buffer freed at the previous barrier
        if (t + 1 < nkt)
            stage_tile(Ab, Bb, lda, ldb, (t + 1) << 6, As[nxt], Bs[nxt], tid);
        __builtin_amdgcn_sched_barrier(0);   // reads+stages stay above MFMA

        // kk=0 cluster: gated by compiler's counted lgkmcnt on first batch
        __builtin_amdgcn_s_setprio(1);
#pragma unroll
        for (int mi = 0; mi < 8; mi++)
#pragma unroll
            for (int ni = 0; ni < 4; ni++)
                acc[mi][ni] = __builtin_amdgcn_mfma_f32_16x16x32_bf16(
                    af[mi][0], bq[ni][0], acc[mi][ni], 0, 0, 0);
        __builtin_amdgcn_s_setprio(0);
        __builtin_amdgcn_sched_barrier(0);   // keep kk clusters separate

        // kk=1 cluster: its reads were issued ~one cluster ago
        __builtin_amdgcn_s_setprio(1);
#pragma unroll
        for (int mi = 0; mi < 8; mi++)
#pragma unroll
            for (int ni = 0; ni < 4; ni++)
                acc[mi][ni] = __builtin_amdgcn_mfma_f32_16x16x32_bf16(
                    af[mi][1], bq[ni][1], acc[mi][ni], 0, 0, 0);
        __builtin_amdgcn_s_setprio(0);
        __builtin_amdgcn_sched_barrier(0);

        // single boundary barrier: drains vmcnt (stages aged a full tile)
        // and publishes buf[nxt]; protects stages of t+2 into buf[cur].
        if (t + 1 < nkt) __syncthreads();
    }

    // epilogue: D element (row = q*4 + r, col = lane&15)
    const int ldc = d->ldc;
#pragma unroll
    for (int mi = 0; mi < 8; mi++) {
#pragma unroll
        for (int ni = 0; ni < 4; ni++) {
            floatx4 v = acc[mi][ni];
            int col  = bn * 256 + wn * 64 + ni * 16 + r16;
            int rowb = bm * 256 + wm * 128 + mi * 16 + q * 4;
            if (d->epi == 0) {
                u16* C = (u16*)d->C;
#pragma unroll
                for (int r = 0; r < 4; r++)
                    C[(size_t)(rowb + r) * ldc + col] = f2b(v[r] * d->alpha);
            } else {
                float* C = (float*)d->C;
#pragma unroll
                for (int r = 0; r < 4; r++)
                    C[(size_t)(rowb + r) * ldc + col] = v[r];
            }
        }
    }
}

// ---------------------------------------------------------------------------
// Double softmax, branch-routed: grid = 3*4096 blocks; branch = bid>>12.
// Row = 4096 bf16 at stride ldS, in-place. Mask: fp32 mF (!=0) or bit mask mB.
// ---------------------------------------------------------------------------
struct SmDesc { u16* S; const float* mF; const u32* mB; };

__device__ __forceinline__ float blockMax(float x, volatile float* red) {
#pragma unroll
    for (int off = 32; off > 0; off >>= 1) x = fmaxf(x, __shfl_xor(x, off, 64));
    __syncthreads();
    if ((threadIdx.x & 63) == 0) red[threadIdx.x >> 6] = x;
    __syncthreads();
    return fmaxf(fmaxf(red[0], red[1]), fmaxf(red[2], red[3]));
}
__device__ __forceinline__ float blockSum(float x, volatile float* red) {
#pragma unroll
    for (int off = 32; off > 0; off >>= 1) x += __shfl_xor(x, off, 64);
    __syncthreads();
    if ((threadIdx.x & 63) == 0) red[threadIdx.x >> 6] = x;
    __syncthreads();
    return red[0] + red[1] + red[2] + red[3];
}

__global__ __launch_bounds__(256)
void dsoftmax3(SmDesc d0, SmDesc d1, SmDesc d2, int ldS)
{
    __shared__ float red[4];
    const int bid = blockIdx.x;
    const int br  = bid >> 12;
    const int row = bid & 4095;
    const SmDesc d = (br == 0) ? d0 : (br == 1) ? d1 : d2;
    u16* Srow = d.S + (size_t)row * ldS;
    const int t = threadIdx.x;

    float v[16];
    uint4 u0 = ((const uint4*)Srow)[t * 2];
    uint4 u1 = ((const uint4*)Srow)[t * 2 + 1];
    unpack8(u0, v); unpack8(u1, v + 8);

    float m = -1e30f;
#pragma unroll
    for (int j = 0; j < 16; j++) m = fmaxf(m, v[j]);
    m = blockMax(m, red);

    float s = 0.f;
#pragma unroll
    for (int j = 0; j < 16; j++) { v[j] = __expf(v[j] - m); s += v[j]; }
    s = blockSum(s, red);
    float rz = 1.0f / s;

    float v2[16];
    if (d.mF) {
        const float* mrow = d.mF + (size_t)row * NS;
#pragma unroll
        for (int k = 0; k < 4; k++) {
            float4 mv = ((const float4*)mrow)[t * 4 + k];
            v2[k * 4 + 0] = (mv.x != 0.f) ? v[k * 4 + 0] * rz : 0.f;
            v2[k * 4 + 1] = (mv.y != 0.f) ? v[k * 4 + 1] * rz : 0.f;
            v2[k * 4 + 2] = (mv.z != 0.f) ? v[k * 4 + 2] * rz : 0.f;
            v2[k * 4 + 3] = (mv.w != 0.f) ? v[k * 4 + 3] * rz : 0.f;
        }
    } else {
        u32 w = d.mB[(size_t)row * (NS / 32) + (t >> 1)];
        u32 half = (w >> ((t & 1) * 16)) & 0xffffu;
#pragma unroll
        for (int j = 0; j < 16; j++)
            v2[j] = ((half >> j) & 1u) ? v[j] * rz : 0.f;
    }

    // second softmax: masked entries are logit 0 (still contribute exp)
    float m2 = -1e30f;
#pragma unroll
    for (int j = 0; j < 16; j++) m2 = fmaxf(m2, v2[j]);
    m2 = blockMax(m2, red);
    float s2 = 0.f;
#pragma unroll
    for (int j = 0; j < 16; j++) { v2[j] = __expf(v2[j] - m2); s2 += v2[j]; }
    s2 = blockSum(s2, red);
    float rz2 = 1.0f / s2;

    uint4 o0, o1;
    o0.x = packb(v2[0] * rz2,  v2[1] * rz2);
    o0.y = packb(v2[2] * rz2,  v2[3] * rz2);
    o0.z = packb(v2[4] * rz2,  v2[5] * rz2);
    o0.w = packb(v2[6] * rz2,  v2[7] * rz2);
    o1.x = packb(v2[8] * rz2,  v2[9] * rz2);
    o1.y = packb(v2[10] * rz2, v2[11] * rz2);
    o1.z = packb(v2[12] * rz2, v2[13] * rz2);
    o1.w = packb(v2[14] * rz2, v2[15] * rz2);
    ((uint4*)Srow)[t * 2]     = o0;
    ((uint4*)Srow)[t * 2 + 1] = o1;
}

// ---------------------------------------------------------------------------
// fp32 [NS,DF] x3 -> bf16 [3*NS, DF] contiguous
// ---------------------------------------------------------------------------
__global__ __launch_bounds__(256)
void cvt_h3(const float* __restrict__ X0, const float* __restrict__ X1,
            const float* __restrict__ X2, u16* __restrict__ Y)
{
    const float* X = (blockIdx.z == 0) ? X0 : (blockIdx.z == 1) ? X1 : X2;
    u16* Yb = Y + (size_t)blockIdx.z * NS * DF;
    int i = blockIdx.x * 256 + threadIdx.x;       // float4 index
    float4 x = ((const float4*)X)[i];
    ushort4 y;
    y.x = f2b(x.x); y.y = f2b(x.y); y.z = f2b(x.z); y.w = f2b(x.w);
    ((ushort4*)Yb)[i] = y;
}

// bit-packed transposed nonzero mask: MT[c*(n/32)+w] bit b = (X[w*32+b][c]!=0)
__global__ __launch_bounds__(256)
void mask_bits(const float* __restrict__ X, u32* __restrict__ MT, int n)
{
    __shared__ float tile[32][33];
    const int tx = threadIdx.x, ty = threadIdx.y;
    const int bx = blockIdx.x * 32, by = blockIdx.y * 32;
#pragma unroll
    for (int k = 0; k < 4; k++) {
        int r = by + ty + k * 8;
        tile[ty + k * 8][tx] = X[(size_t)r * n + bx + tx];
    }
    __syncthreads();
#pragma unroll
    for (int k = 0; k < 4; k++) {
        int c = bx + ty + k * 8;
        unsigned long long m = __ballot(tile[tx][ty + k * 8] != 0.f);
        u32 w = (ty & 1) ? (u32)(m >> 32) : (u32)m;
        if (tx == 0) MT[(size_t)c * (n / 32) + (by >> 5)] = w;
    }
}

__global__ __launch_bounds__(256)
void cvtk(const float* __restrict__ X, u16* __restrict__ Y, int n4)
{
    int i = blockIdx.x * 256 + threadIdx.x;
    if (i >= n4) return;
    float4 x = ((const float4*)X)[i];
    ushort4 y;
    y.x = f2b(x.x); y.y = f2b(x.y); y.z = f2b(x.z); y.w = f2b(x.w);
    ((ushort4*)Y)[i] = y;
}

// out = tanh(out + P1 + P2 + P3 + bias[col]); 4096x1024 fp32, float4/thread.
__global__ __launch_bounds__(256)
void combine4(const float* __restrict__ P1, const float* __restrict__ P2,
              const float* __restrict__ P3, const float* __restrict__ bias,
              float* __restrict__ out)
{
    int i = blockIdx.x * 256 + threadIdx.x;       // float4 index
    float4 a = ((const float4*)out)[i];
    float4 b = ((const float4*)P1)[i];
    float4 c = ((const float4*)P2)[i];
    float4 e = ((const float4*)P3)[i];
    float4 bb = ((const float4*)bias)[i & 255];   // 1024 cols = 256 float4
    float4 o;
    o.x = tanhf(a.x + b.x + c.x + e.x + bb.x);
    o.y = tanhf(a.y + b.y + c.y + e.y + bb.y);
    o.z = tanhf(a.z + b.z + c.z + e.z + bb.z);
    o.w = tanhf(a.w + b.w + c.w + e.w + bb.w);
    ((float4*)out)[i] = o;
}

// ---------------------------------------------------------------------------
static inline GemmDesc mk8(const u16* A, const u16* B, void* C,
                           int K, int lda, int ldb, int ldc,
                           int nTX, int nTY, int epi, float alpha,
                           int colMajor)
{
    GemmDesc d;
    d.A = A; d.B = B; d.C = C; d.bias = nullptr;
    d.K = K; d.lda = lda; d.ldb = ldb; d.ldc = ldc;
    d.nTilesX = nTX; d.nTilesY = nTY; d.nBlocks = nTX * nTY;
    d.colMajor = colMajor; d.epi = epi; d.alpha = alpha;
    return d;
}

extern "C" void kernel_launch(void* const* d_in, const int* in_sizes, int n_in,
                              void* d_out, int out_size, void* d_ws, size_t ws_size,
                              hipStream_t stream)
{
    const float* L      = (const float*)d_in[0];
    const float* H      = (const float*)d_in[1];
    const float* B_low  = (const float*)d_in[2];
    const float* H_low  = (const float*)d_in[3];
    const float* B_high = (const float*)d_in[4];
    const float* H_high = (const float*)d_in[5];
    const float* W      = (const float*)d_in[6];
    const float* bvec   = (const float*)d_in[7];
    float* out = (float*)d_out;

    const size_t MB = 1024 * 1024;
    char* ws = (char*)d_ws;
    dim3 bt(32, 8);

    // ---- workspace layout (168 MB peak, 176 MB budget) ----
    u16* S    = (u16*)(ws + 0);             // 96 MB [4096, 12288] bf16
    u16* Hcat = (u16*)(ws + 96 * MB);       // 24 MB [12288, 1024] bf16
    u16* Wb   = (u16*)(ws + 120 * MB);      //  6 MB [1024, 3072] bf16
    u32* mlT  = (u32*)(ws + 126 * MB);      //  2 MB bit mask
    u16* GT   = (u16*)(ws + 128 * MB);      // 24 MB [1024, 12288] bf16
    float* P1 = (float*)(ws + 96 * MB);     // 16 MB (over dead Hcat)
    float* P2 = (float*)(ws + 112 * MB);    // 16 MB (over dead Hcat/Wb/mlT)
    float* P3 = (float*)(ws + 152 * MB);    // 16 MB

    cvt_h3<<<dim3(NS * DF / 4 / 256, 1, 3), 256, 0, stream>>>(H, H_low, H_high, Hcat);
    cvtk<<<(DF * 3 * DF / 4 + 255) / 256, 256, 0, stream>>>(W, Wb, DF * 3 * DF / 4);
    mask_bits<<<dim3(NS / 32, NS / 32), bt, 0, stream>>>(B_low, mlT, NS);

    // launch1: S = (Hcat @ Hcat^T)/32 (768 blocks) and
    //          GT_b = W_b-block @ KV_b^T (3 x 64 blocks), all K=1024 uniform.
    GemmDesc sg = mk8(Hcat, Hcat, S, DF, DF, DF, 3 * NS,
                      3 * NS / 256, NS / 256, 0, 0.03125f, 1);
    GemmDesc g0 = mk8(Wb,          Hcat,               GT,          DF, 3 * DF, DF, 3 * NS, NS / 256, DF / 256, 0, 1.0f, 1);
    GemmDesc g1 = mk8(Wb + DF,     Hcat + NS * DF,     GT + NS,     DF, 3 * DF, DF, 3 * NS, NS / 256, DF / 256, 0, 1.0f, 1);
    GemmDesc g2 = mk8(Wb + 2 * DF, Hcat + 2 * NS * DF, GT + 2 * NS, DF, 3 * DF, DF, 3 * NS, NS / 256, DF / 256, 0, 1.0f, 1);
    mgemm8<<<sg.nBlocks + g0.nBlocks + g1.nBlocks + g2.nBlocks, 512, 0, stream>>>(sg, g0, g1, g2);

    // fused double softmax over 12288 rows (row stride 12288), in place
    SmDesc s0 = {S,          L,       nullptr};
    SmDesc s1 = {S + NS,     nullptr, mlT};
    SmDesc s2 = {S + 2 * NS, B_high,  nullptr};
    dsoftmax3<<<3 * NS, 256, 0, stream>>>(s0, s1, s2, 3 * NS);

    // launch2: out_pre = A_all @ GT^T, split-K x4 (K=3072 chunks), 256 blocks
    GemmDesc f0 = mk8(S,          GT,          out, 3 * DF, 3 * NS, 3 * NS, DF, DF / 256, NS / 256, 1, 1.0f, 1);
    GemmDesc f1 = mk8(S + 3 * DF, GT + 3 * DF, P1,  3 * DF, 3 * NS, 3 * NS, DF, DF / 256, NS / 256, 1, 1.0f, 1);
    GemmDesc f2 = mk8(S + 6 * DF, GT + 6 * DF, P2,  3 * DF, 3 * NS, 3 * NS, DF, DF / 256, NS / 256, 1, 1.0f, 1);
    GemmDesc f3 = mk8(S + 9 * DF, GT + 9 * DF, P3,  3 * DF, 3 * NS, 3 * NS, DF, DF / 256, NS / 256, 1, 1.0f, 1);
    mgemm8f<<<f0.nBlocks + f1.nBlocks + f2.nBlocks + f3.nBlocks, 512, 0, stream>>>(f0, f1, f2, f3);

    // out = tanh(out + P1 + P2 + P3 + bias)
    combine4<<<NS * DF / 4 / 256, 256, 0, stream>>>(P1, P2, P3, bvec, out);
}